// Round 7
// baseline (855.906 us; speedup 1.0000x reference)
//
#include <hip/hip_runtime.h>

// GCN_88734024335852 — 2-layer GCN on MI355X
//
// R7: R6 crashed on a ws-layout bug (gbuf is 16n ushorts = 8n floats, was
// allocated 2n -> k_gemm1 clobbered gcnt/ebuf -> OOB fault). Fixed layout;
// algorithm unchanged from R6:
// gather a bf16 copy of g (3.2MB -> fits per-XCD L2, ~200cyc) with 2
// lanes/edge x 16B (2 req/edge, was 4). LDS acc stride 17. fp32 g kept
// for the self-loop term.
//
//   dinv[i] = rsqrt(deg_in[i]+1)
//   layer out[c] = dinv[c] * ( g[c] + sum_{col[e]==c} g[row[e]] ) + b
//   g[i] = (h[i] @ W) * dinv[i]
//
// ws (floats): xe[n] dinv[n] g[16n] g2[n] acc1[16n] acc2[n] gbuf[8n]
//              gcnt/gstart/gcursor[nb*16] ebuf[ne]   (~43 MB)

#define D_FEAT 128
#define HIDDEN 16
#define TILE 8192
#define NCH 8

__global__ __launch_bounds__(256) void k_init(float* xe, float* acc1, float* acc2,
                                              unsigned* gcnt, int n, int nb16) {
    int t = blockIdx.x * 256 + threadIdx.x;
    if (t < 16 * n) acc1[t] = 0.f;
    if (t < n) { xe[t] = 0.f; acc2[t] = 0.f; }
    if (t < nb16) gcnt[t] = 0u;
}

// Fused: xe segment-sum (rows sorted -> wave scan) + bucket histogram.
__global__ __launch_bounds__(256) void k_prep(const int* __restrict__ row,
                                              const int* __restrict__ col,
                                              const float* __restrict__ ea,
                                              float* xe, unsigned* gcnt, int ne, int nb) {
    __shared__ unsigned h[512];
    int tid = threadIdx.x;
    h[tid] = 0u; h[tid + 256] = 0u;
    __syncthreads();
    int lane = tid & 63;
    int tile0 = blockIdx.x * TILE;
    for (int k = 0; k < TILE / 256; ++k) {
        int e = tile0 + k * 256 + tid;
        bool valid = e < ne;
        int r = valid ? row[e] : -1;
        float a = valid ? ea[e] : 0.f;
        if (valid) atomicAdd(&h[col[e] >> 8], 1u);
        #pragma unroll
        for (int d = 1; d < 64; d <<= 1) {
            float up = __shfl_up(a, d);
            int  rup = __shfl_up(r, d);
            if (lane >= d && rup == r) a += up;
        }
        int rdn = __shfl_down(r, 1);
        bool tail = (lane == 63) || (rdn != r);
        if (valid && tail) unsafeAtomicAdd(&xe[r], a);
    }
    __syncthreads();
    for (int b = tid; b < nb; b += 256)
        if (h[b]) atomicAdd(&gcnt[b * 16], h[b]);
}

// Exclusive scan of bucket counts (single block).
__global__ __launch_bounds__(512) void k_scan(const unsigned* gcnt, unsigned* gstart,
                                              unsigned* gcursor, int nb) {
    __shared__ unsigned sc[512], hh[512];
    int tid = threadIdx.x;
    unsigned v = (tid < nb) ? gcnt[tid * 16] : 0u;
    hh[tid] = v; sc[tid] = v;
    __syncthreads();
    for (int off = 1; off < 512; off <<= 1) {
        unsigned u = (tid >= off) ? sc[tid - off] : 0u;
        __syncthreads();
        sc[tid] += u;
        __syncthreads();
    }
    if (tid < nb) {
        unsigned ex = sc[tid] - hh[tid];
        gstart[tid * 16] = ex;
        gcursor[tid * 16] = ex;
    }
}

// Tile counting sort: stage bucket-ordered in LDS, coalesced run writes.
__global__ __launch_bounds__(512) void k_place(const int* __restrict__ row,
                                               const int* __restrict__ col,
                                               unsigned* gcursor, unsigned* ebuf,
                                               int ne, int nb) {
    __shared__ unsigned stage[TILE];
    __shared__ unsigned short sbuck[TILE];
    __shared__ unsigned h[512], sc[512], base_[512], cursor[512], gb_[512];
    int tid = threadIdx.x;
    int tile0 = blockIdx.x * TILE;
    int cnt_t = min(TILE, ne - tile0);
    h[tid] = 0u;
    __syncthreads();
    int rr[16], cc[16];
    #pragma unroll
    for (int k = 0; k < 16; ++k) {
        int e = tile0 + tid + k * 512;
        if (e < ne) {
            rr[k] = row[e]; cc[k] = col[e];
            atomicAdd(&h[cc[k] >> 8], 1u);
        } else rr[k] = -1;
    }
    __syncthreads();
    sc[tid] = h[tid];
    __syncthreads();
    for (int off = 1; off < 512; off <<= 1) {
        unsigned u = (tid >= off) ? sc[tid - off] : 0u;
        __syncthreads();
        sc[tid] += u;
        __syncthreads();
    }
    unsigned ex = sc[tid] - h[tid];
    base_[tid] = ex;
    cursor[tid] = ex;
    if (tid < nb && h[tid]) gb_[tid] = atomicAdd(&gcursor[tid * 16], h[tid]);
    __syncthreads();
    #pragma unroll
    for (int k = 0; k < 16; ++k) {
        if (rr[k] >= 0) {
            int b = cc[k] >> 8;
            unsigned p = atomicAdd(&cursor[b], 1u);
            stage[p] = (((unsigned)(cc[k] & 255)) << 24) | (unsigned)rr[k];
            sbuck[p] = (unsigned short)b;
        }
    }
    __syncthreads();
    for (int t = tid; t < cnt_t; t += 512) {
        int b = sbuck[t];
        ebuf[gb_[b] + ((unsigned)t - base_[b])] = stage[t];
    }
}

// Per-bucket in-degree -> dinv.
__global__ __launch_bounds__(256) void k_deg_dinv(const unsigned* __restrict__ ebuf,
                                                  const unsigned* gcnt, const unsigned* gstart,
                                                  float* dinv, int n) {
    __shared__ unsigned dg[256];
    int b = blockIdx.x, tid = threadIdx.x;
    dg[tid] = 0u;
    __syncthreads();
    unsigned m = gcnt[b * 16], base = gstart[b * 16];
    for (unsigned i = tid; i < m; i += 256) atomicAdd(&dg[ebuf[base + i] >> 24], 1u);
    __syncthreads();
    int node = b * 256 + tid;
    if (node < n) dinv[node] = rsqrtf((float)dg[tid] + 1.0f);
}

// g[i][j] = (sum_k x[i][k]*W1[k][j] + xe[i]*W1[128][j]) * dinv[i]
// Writes fp32 g (self-term) and bf16 gbuf (gather copy, RNE).
__global__ __launch_bounds__(256) void k_gemm1(const float* __restrict__ x,
                                               const float* __restrict__ xe,
                                               const float* __restrict__ dinv,
                                               const float* __restrict__ W1,
                                               float* __restrict__ g,
                                               unsigned short* __restrict__ gb, int n) {
    __shared__ float Ws[129 * 16];
    __shared__ float xs[64 * 132];
    int tid = threadIdx.x;
    for (int idx = tid; idx < 129 * 16; idx += 256) Ws[idx] = W1[idx];
    int n0 = blockIdx.x * 64;
    const float4* x4 = (const float4*)x;
    for (int idx = tid; idx < 64 * 32; idx += 256) {
        int r = idx >> 5, c = idx & 31;
        float4 v = (n0 + r < n) ? x4[(size_t)(n0 + r) * 32 + c]
                                : make_float4(0.f, 0.f, 0.f, 0.f);
        *(float4*)&xs[r * 132 + c * 4] = v;
    }
    if (tid < 64) {
        int r = tid;
        xs[r * 132 + 128] = (n0 + r < n) ? xe[n0 + r] : 0.f;
    }
    __syncthreads();
    int j  = tid & 15;
    int nb = tid >> 4;
    for (int rep = 0; rep < 4; ++rep) {
        int nl = nb + (rep << 4);
        int node = n0 + nl;
        const float* xrow = &xs[nl * 132];
        float acc = 0.f;
        #pragma unroll
        for (int k = 0; k < 128; k += 4) {
            float4 xv = *(const float4*)&xrow[k];
            acc += xv.x * Ws[(k + 0) * 16 + j];
            acc += xv.y * Ws[(k + 1) * 16 + j];
            acc += xv.z * Ws[(k + 2) * 16 + j];
            acc += xv.w * Ws[(k + 3) * 16 + j];
        }
        acc += xrow[128] * Ws[128 * 16 + j];
        if (node < n) {
            float v = acc * dinv[node];
            g[(size_t)node * 16 + j] = v;
            union { float f; unsigned u; } cv; cv.f = v;
            unsigned r16 = (cv.u + 0x7FFFu + ((cv.u >> 16) & 1u)) >> 16;
            gb[(size_t)node * 16 + j] = (unsigned short)r16;
        }
    }
}

__device__ inline void add8(float* a, uint4 w) {
    union { unsigned u; float f; } t;
    t.u = w.x << 16;          unsafeAtomicAdd(a + 0, t.f);
    t.u = w.x & 0xFFFF0000u;  unsafeAtomicAdd(a + 1, t.f);
    t.u = w.y << 16;          unsafeAtomicAdd(a + 2, t.f);
    t.u = w.y & 0xFFFF0000u;  unsafeAtomicAdd(a + 3, t.f);
    t.u = w.z << 16;          unsafeAtomicAdd(a + 4, t.f);
    t.u = w.z & 0xFFFF0000u;  unsafeAtomicAdd(a + 5, t.f);
    t.u = w.w << 16;          unsafeAtomicAdd(a + 6, t.f);
    t.u = w.w & 0xFFFF0000u;  unsafeAtomicAdd(a + 7, t.f);
}

// Layer-1 aggregation: block (b, ch); 2 lanes/edge, 16B bf16 gathers
// (2 requests/edge, 3.2MB footprint -> per-XCD L2 resident). LDS acc
// stride 17 (bank-spread). Flush via coalesced global atomics.
__global__ __launch_bounds__(256) void k_agg16e(const unsigned* __restrict__ ebuf,
                                                const unsigned* gcnt, const unsigned* gstart,
                                                const unsigned short* __restrict__ gb,
                                                float* __restrict__ acc1, int nb) {
    __shared__ float acc[256 * 17];
    int b = blockIdx.x, ch = blockIdx.y, tid = threadIdx.x;
    for (int k = tid; k < 256 * 17; k += 256) acc[k] = 0.f;
    __syncthreads();
    unsigned m = gcnt[b * 16], base = gstart[b * 16];
    unsigned e0 = (unsigned)(((unsigned long long)m * ch) / NCH);
    unsigned e1 = (unsigned)(((unsigned long long)m * (ch + 1)) / NCH);
    const uint4* gb4 = (const uint4*)gb;   // 16B = 8 bf16 = half a row
    int q = tid & 1;
    unsigned i = e0 + (tid >> 1);          // 128 edges per 256-thread step
    for (; i + 384 < e1; i += 512) {
        unsigned pk0 = ebuf[base + i];
        unsigned pk1 = ebuf[base + i + 128];
        unsigned pk2 = ebuf[base + i + 256];
        unsigned pk3 = ebuf[base + i + 384];
        uint4 v0 = gb4[(size_t)(pk0 & 0xFFFFFFu) * 2 + q];
        uint4 v1 = gb4[(size_t)(pk1 & 0xFFFFFFu) * 2 + q];
        uint4 v2 = gb4[(size_t)(pk2 & 0xFFFFFFu) * 2 + q];
        uint4 v3 = gb4[(size_t)(pk3 & 0xFFFFFFu) * 2 + q];
        add8(&acc[(pk0 >> 24) * 17 + q * 8], v0);
        add8(&acc[(pk1 >> 24) * 17 + q * 8], v1);
        add8(&acc[(pk2 >> 24) * 17 + q * 8], v2);
        add8(&acc[(pk3 >> 24) * 17 + q * 8], v3);
    }
    for (; i < e1; i += 128) {
        unsigned pk = ebuf[base + i];
        uint4 v = gb4[(size_t)(pk & 0xFFFFFFu) * 2 + q];
        add8(&acc[(pk >> 24) * 17 + q * 8], v);
    }
    __syncthreads();
    float* dst = acc1 + (size_t)b * 4096;
    #pragma unroll
    for (int k = 0; k < 16; ++k) {
        int lin = tid + k * 256;
        float v = acc[(lin >> 4) * 17 + (lin & 15)];
        if (v != 0.f) unsafeAtomicAdd(&dst[lin], v);   // v==0 guard also protects
    }                                                  // the b==nb-1 OOB tail
}

// Epilogue: h1 = relu(dinv*(g+acc1)+b1); g2 = (h1@W2)*dinv.
__global__ __launch_bounds__(256) void k_layer1_post(const float* __restrict__ acc1,
                                                     const float* __restrict__ g,
                                                     const float* __restrict__ dinv,
                                                     const float* __restrict__ b1,
                                                     const float* __restrict__ W2,
                                                     float* __restrict__ g2, int n) {
    int t = blockIdx.x * 256 + threadIdx.x;
    int i = t >> 4, j = t & 15;
    if (i >= n) return;
    float di = dinv[i];
    float v = di * (g[(size_t)i * 16 + j] + acc1[(size_t)i * 16 + j]) + b1[j];
    v = fmaxf(v, 0.f);
    float p = v * W2[j];
    p += __shfl_down(p, 8, 16);
    p += __shfl_down(p, 4, 16);
    p += __shfl_down(p, 2, 16);
    p += __shfl_down(p, 1, 16);
    if (j == 0) g2[i] = p * di;
}

// Layer-2 aggregation, chunked; flush coalesced atomics into acc2.
__global__ __launch_bounds__(256) void k_agg1d(const unsigned* __restrict__ ebuf,
                                               const unsigned* gcnt, const unsigned* gstart,
                                               const float* __restrict__ g2,
                                               float* __restrict__ acc2, int nb) {
    __shared__ float a2[256];
    int b = blockIdx.x, ch = blockIdx.y, tid = threadIdx.x;
    a2[tid] = 0.f;
    __syncthreads();
    unsigned m = gcnt[b * 16], base = gstart[b * 16];
    unsigned e0 = (unsigned)(((unsigned long long)m * ch) / NCH);
    unsigned e1 = (unsigned)(((unsigned long long)m * (ch + 1)) / NCH);
    unsigned i = e0 + tid;
    for (; i + 768 < e1; i += 1024) {
        unsigned pk0 = ebuf[base + i];
        unsigned pk1 = ebuf[base + i + 256];
        unsigned pk2 = ebuf[base + i + 512];
        unsigned pk3 = ebuf[base + i + 768];
        float v0 = g2[pk0 & 0xFFFFFFu];
        float v1 = g2[pk1 & 0xFFFFFFu];
        float v2 = g2[pk2 & 0xFFFFFFu];
        float v3 = g2[pk3 & 0xFFFFFFu];
        unsafeAtomicAdd(&a2[pk0 >> 24], v0);
        unsafeAtomicAdd(&a2[pk1 >> 24], v1);
        unsafeAtomicAdd(&a2[pk2 >> 24], v2);
        unsafeAtomicAdd(&a2[pk3 >> 24], v3);
    }
    for (; i < e1; i += 256) {
        unsigned pk = ebuf[base + i];
        unsafeAtomicAdd(&a2[pk >> 24], g2[pk & 0xFFFFFFu]);
    }
    __syncthreads();
    float v = a2[tid];
    if (v != 0.f) unsafeAtomicAdd(&acc2[b * 256 + tid], v);
}

__global__ __launch_bounds__(256) void k_out(const float* __restrict__ acc2,
                                             const float* __restrict__ dinv,
                                             const float* __restrict__ g2,
                                             const float* __restrict__ b2,
                                             float* __restrict__ out, int n) {
    int i = blockIdx.x * 256 + threadIdx.x;
    if (i >= n) return;
    out[i] = dinv[i] * (g2[i] + acc2[i]) + b2[0];
}

extern "C" void kernel_launch(void* const* d_in, const int* in_sizes, int n_in,
                              void* d_out, int out_size, void* d_ws, size_t ws_size,
                              hipStream_t stream) {
    const float* x   = (const float*)d_in[0];
    const float* ea  = (const float*)d_in[1];
    const int*   row = (const int*)d_in[2];
    const int*   col = (const int*)d_in[3];
    const float* W1  = (const float*)d_in[4];
    const float* b1  = (const float*)d_in[5];
    const float* W2  = (const float*)d_in[6];
    const float* b2  = (const float*)d_in[7];
    float* out = (float*)d_out;

    int n  = in_sizes[0] / D_FEAT;   // 100000
    int ne = in_sizes[2];            // 6400000
    int nb = (n + 255) >> 8;         // 391 buckets of 256 nodes

    float* ws   = (float*)d_ws;
    float* xe   = ws;                      // n
    float* dinv = ws + (size_t)n;          // n
    float* g    = ws + (size_t)2 * n;      // 16n
    float* g2   = ws + (size_t)18 * n;     // n
    float* acc1 = ws + (size_t)19 * n;     // 16n
    float* acc2 = ws + (size_t)35 * n;     // n
    unsigned short* gbuf = (unsigned short*)(ws + (size_t)36 * n);  // 16n ushort = 8n floats
    unsigned* gcnt    = (unsigned*)(ws + (size_t)44 * n);  // nb*16
    unsigned* gstart  = gcnt + (size_t)nb * 16;
    unsigned* gcursor = gstart + (size_t)nb * 16;
    unsigned* ebuf    = gcursor + (size_t)nb * 16;         // ne

    dim3 blk(256);
    int g_init = (16 * n + 255) / 256;
    int g_tile = (ne + TILE - 1) / TILE;
    int g_gemm = (n + 63) / 64;
    int g_n16  = (n * HIDDEN + 255) / 256;
    int g_node = (n + 255) / 256;

    k_init<<<g_init, blk, 0, stream>>>(xe, acc1, acc2, gcnt, n, nb * 16);
    k_prep<<<g_tile, blk, 0, stream>>>(row, col, ea, xe, gcnt, ne, nb);
    k_scan<<<1, 512, 0, stream>>>(gcnt, gstart, gcursor, nb);
    k_place<<<g_tile, 512, 0, stream>>>(row, col, gcursor, ebuf, ne, nb);
    k_deg_dinv<<<nb, blk, 0, stream>>>(ebuf, gcnt, gstart, dinv, n);
    k_gemm1<<<g_gemm, blk, 0, stream>>>(x, xe, dinv, W1, g, gbuf, n);
    k_agg16e<<<dim3(nb, NCH), blk, 0, stream>>>(ebuf, gcnt, gstart, gbuf, acc1, nb);
    k_layer1_post<<<g_n16, blk, 0, stream>>>(acc1, g, dinv, b1, W2, g2, n);
    k_agg1d<<<dim3(nb, NCH), blk, 0, stream>>>(ebuf, gcnt, gstart, g2, acc2, nb);
    k_out<<<g_node, blk, 0, stream>>>(acc2, dinv, g2, b2, out, n);
}

// Round 8
// 388.141 us; speedup vs baseline: 2.2051x; 2.2051x over previous
//
#include <hip/hip_runtime.h>

// GCN_88734024335852 — 2-layer GCN on MI355X
//
// R8: R4/R5/R7 all landed ~550us regardless of gather layout -> the agg was
// bound by its 16 LDS-atomic lane-ops/edge (1.64G total, ~13cyc/wave-op).
// Fix: full counting sort by destination (bucket pass + in-bucket pass ->
// CSR ptr[]), then aggregation = register segmented reduction (16 lanes/node,
// lane j owns feature j; 1 coalesced bf16 row load + 1 FMA per edge, ZERO
// LDS atomics). Epilogues fused into the agg kernels.
//
//   dinv[i] = rsqrt(deg_in[i]+1)
//   layer out[c] = dinv[c] * ( g[c] + sum_{col[e]==c} g[row[e]] ) + b
//   g[i] = (h[i] @ W) * dinv[i]
//
// ws (floats): xe[n] dinv[n] g[16n] g2[n] gbuf[8n(bf16 16n)] ptr[nb*256+1]
//              gcnt/gstart/gcursor[nb*16] ebuf[ne] ebuf2[ne]   (~63 MB)

#define D_FEAT 128
#define HIDDEN 16
#define TILE 8192

__device__ inline float bf2f(unsigned short u) {
    union { unsigned x; float f; } t; t.x = ((unsigned)u) << 16; return t.f;
}

__global__ __launch_bounds__(256) void k_init(float* xe, unsigned* gcnt, int n, int nb16) {
    int t = blockIdx.x * 256 + threadIdx.x;
    if (t < n) xe[t] = 0.f;
    if (t < nb16) gcnt[t] = 0u;
}

// Fused: xe segment-sum (rows sorted -> wave scan) + bucket histogram.
__global__ __launch_bounds__(256) void k_prep(const int* __restrict__ row,
                                              const int* __restrict__ col,
                                              const float* __restrict__ ea,
                                              float* xe, unsigned* gcnt, int ne, int nb) {
    __shared__ unsigned h[512];
    int tid = threadIdx.x;
    h[tid] = 0u; h[tid + 256] = 0u;
    __syncthreads();
    int lane = tid & 63;
    int tile0 = blockIdx.x * TILE;
    for (int k = 0; k < TILE / 256; ++k) {
        int e = tile0 + k * 256 + tid;
        bool valid = e < ne;
        int r = valid ? row[e] : -1;
        float a = valid ? ea[e] : 0.f;
        if (valid) atomicAdd(&h[col[e] >> 8], 1u);
        #pragma unroll
        for (int d = 1; d < 64; d <<= 1) {
            float up = __shfl_up(a, d);
            int  rup = __shfl_up(r, d);
            if (lane >= d && rup == r) a += up;
        }
        int rdn = __shfl_down(r, 1);
        bool tail = (lane == 63) || (rdn != r);
        if (valid && tail) unsafeAtomicAdd(&xe[r], a);
    }
    __syncthreads();
    for (int b = tid; b < nb; b += 256)
        if (h[b]) atomicAdd(&gcnt[b * 16], h[b]);
}

// Exclusive scan of bucket counts (single block).
__global__ __launch_bounds__(512) void k_scan(const unsigned* gcnt, unsigned* gstart,
                                              unsigned* gcursor, int nb) {
    __shared__ unsigned sc[512], hh[512];
    int tid = threadIdx.x;
    unsigned v = (tid < nb) ? gcnt[tid * 16] : 0u;
    hh[tid] = v; sc[tid] = v;
    __syncthreads();
    for (int off = 1; off < 512; off <<= 1) {
        unsigned u = (tid >= off) ? sc[tid - off] : 0u;
        __syncthreads();
        sc[tid] += u;
        __syncthreads();
    }
    if (tid < nb) {
        unsigned ex = sc[tid] - hh[tid];
        gstart[tid * 16] = ex;
        gcursor[tid * 16] = ex;
    }
}

// Tile counting sort: stage bucket-ordered in LDS, coalesced run writes.
__global__ __launch_bounds__(512) void k_place(const int* __restrict__ row,
                                               const int* __restrict__ col,
                                               unsigned* gcursor, unsigned* ebuf,
                                               int ne, int nb) {
    __shared__ unsigned stage[TILE];
    __shared__ unsigned short sbuck[TILE];
    __shared__ unsigned h[512], sc[512], base_[512], cursor[512], gb_[512];
    int tid = threadIdx.x;
    int tile0 = blockIdx.x * TILE;
    int cnt_t = min(TILE, ne - tile0);
    h[tid] = 0u;
    __syncthreads();
    int rr[16], cc[16];
    #pragma unroll
    for (int k = 0; k < 16; ++k) {
        int e = tile0 + tid + k * 512;
        if (e < ne) {
            rr[k] = row[e]; cc[k] = col[e];
            atomicAdd(&h[cc[k] >> 8], 1u);
        } else rr[k] = -1;
    }
    __syncthreads();
    sc[tid] = h[tid];
    __syncthreads();
    for (int off = 1; off < 512; off <<= 1) {
        unsigned u = (tid >= off) ? sc[tid - off] : 0u;
        __syncthreads();
        sc[tid] += u;
        __syncthreads();
    }
    unsigned ex = sc[tid] - h[tid];
    base_[tid] = ex;
    cursor[tid] = ex;
    if (tid < nb && h[tid]) gb_[tid] = atomicAdd(&gcursor[tid * 16], h[tid]);
    __syncthreads();
    #pragma unroll
    for (int k = 0; k < 16; ++k) {
        if (rr[k] >= 0) {
            int b = cc[k] >> 8;
            unsigned p = atomicAdd(&cursor[b], 1u);
            stage[p] = (((unsigned)(cc[k] & 255)) << 24) | (unsigned)rr[k];
            sbuck[p] = (unsigned short)b;
        }
    }
    __syncthreads();
    for (int t = tid; t < cnt_t; t += 512) {
        int b = sbuck[t];
        ebuf[gb_[b] + ((unsigned)t - base_[b])] = stage[t];
    }
}

// Per bucket: exact-col histogram -> CSR ptr + dinv, then scatter rows into
// fully col-sorted ebuf2. (2 LDS atomics per edge total — replaces the
// 16/edge in the old agg loop.)
__global__ __launch_bounds__(256) void k_csr_scatter(const unsigned* __restrict__ ebuf,
                                                     const unsigned* gcnt, const unsigned* gstart,
                                                     unsigned* __restrict__ ptr,
                                                     float* __restrict__ dinv,
                                                     unsigned* __restrict__ ebuf2,
                                                     int n, int nb) {
    __shared__ unsigned dg[256], sc[256], cur[256];
    int b = blockIdx.x, tid = threadIdx.x;
    dg[tid] = 0u;
    __syncthreads();
    unsigned m = gcnt[b * 16], base = gstart[b * 16];
    for (unsigned i = tid; i < m; i += 256) atomicAdd(&dg[ebuf[base + i] >> 24], 1u);
    __syncthreads();
    sc[tid] = dg[tid];
    __syncthreads();
    for (int off = 1; off < 256; off <<= 1) {
        unsigned u = (tid >= off) ? sc[tid - off] : 0u;
        __syncthreads();
        sc[tid] += u;
        __syncthreads();
    }
    unsigned ex = sc[tid] - dg[tid];
    int node = b * 256 + tid;
    ptr[node] = base + ex;
    if (b == nb - 1 && tid == 255) ptr[nb * 256] = base + m;
    if (node < n) dinv[node] = rsqrtf((float)dg[tid] + 1.0f);
    cur[tid] = base + ex;
    __syncthreads();
    unsigned i = tid;
    for (; i + 768 < m; i += 1024) {
        unsigned pk0 = ebuf[base + i];
        unsigned pk1 = ebuf[base + i + 256];
        unsigned pk2 = ebuf[base + i + 512];
        unsigned pk3 = ebuf[base + i + 768];
        unsigned p0 = atomicAdd(&cur[pk0 >> 24], 1u);
        unsigned p1 = atomicAdd(&cur[pk1 >> 24], 1u);
        unsigned p2 = atomicAdd(&cur[pk2 >> 24], 1u);
        unsigned p3 = atomicAdd(&cur[pk3 >> 24], 1u);
        ebuf2[p0] = pk0 & 0xFFFFFFu;
        ebuf2[p1] = pk1 & 0xFFFFFFu;
        ebuf2[p2] = pk2 & 0xFFFFFFu;
        ebuf2[p3] = pk3 & 0xFFFFFFu;
    }
    for (; i < m; i += 256) {
        unsigned pk = ebuf[base + i];
        unsigned p = atomicAdd(&cur[pk >> 24], 1u);
        ebuf2[p] = pk & 0xFFFFFFu;
    }
}

// g[i][j] = (sum_k x[i][k]*W1[k][j] + xe[i]*W1[128][j]) * dinv[i]
// Writes fp32 g (self-term) and bf16 gbuf (gather copy, RNE).
__global__ __launch_bounds__(256) void k_gemm1(const float* __restrict__ x,
                                               const float* __restrict__ xe,
                                               const float* __restrict__ dinv,
                                               const float* __restrict__ W1,
                                               float* __restrict__ g,
                                               unsigned short* __restrict__ gb, int n) {
    __shared__ float Ws[129 * 16];
    __shared__ float xs[64 * 132];
    int tid = threadIdx.x;
    for (int idx = tid; idx < 129 * 16; idx += 256) Ws[idx] = W1[idx];
    int n0 = blockIdx.x * 64;
    const float4* x4 = (const float4*)x;
    for (int idx = tid; idx < 64 * 32; idx += 256) {
        int r = idx >> 5, c = idx & 31;
        float4 v = (n0 + r < n) ? x4[(size_t)(n0 + r) * 32 + c]
                                : make_float4(0.f, 0.f, 0.f, 0.f);
        *(float4*)&xs[r * 132 + c * 4] = v;
    }
    if (tid < 64) {
        int r = tid;
        xs[r * 132 + 128] = (n0 + r < n) ? xe[n0 + r] : 0.f;
    }
    __syncthreads();
    int j  = tid & 15;
    int nb = tid >> 4;
    for (int rep = 0; rep < 4; ++rep) {
        int nl = nb + (rep << 4);
        int node = n0 + nl;
        const float* xrow = &xs[nl * 132];
        float acc = 0.f;
        #pragma unroll
        for (int k = 0; k < 128; k += 4) {
            float4 xv = *(const float4*)&xrow[k];
            acc += xv.x * Ws[(k + 0) * 16 + j];
            acc += xv.y * Ws[(k + 1) * 16 + j];
            acc += xv.z * Ws[(k + 2) * 16 + j];
            acc += xv.w * Ws[(k + 3) * 16 + j];
        }
        acc += xrow[128] * Ws[128 * 16 + j];
        if (node < n) {
            float v = acc * dinv[node];
            g[(size_t)node * 16 + j] = v;
            union { float f; unsigned u; } cv; cv.f = v;
            unsigned r16 = (cv.u + 0x7FFFu + ((cv.u >> 16) & 1u)) >> 16;
            gb[(size_t)node * 16 + j] = (unsigned short)r16;
        }
    }
}

// Layer-1 agg as CSR segmented reduction + fused epilogue.
// 16 lanes per node; lane j owns feature j. Per edge: one coalesced 32B
// bf16 row load + FMA. No LDS, no atomics.
__global__ __launch_bounds__(256) void k_agg16f(const unsigned* __restrict__ ptr,
                                                const unsigned* __restrict__ eb2,
                                                const unsigned short* __restrict__ gb,
                                                const float* __restrict__ g,
                                                const float* __restrict__ dinv,
                                                const float* __restrict__ b1,
                                                const float* __restrict__ W2,
                                                float* __restrict__ g2, int n) {
    int tid = threadIdx.x;
    int grp = tid >> 4, j = tid & 15;
    int v = blockIdx.x * 16 + grp;
    if (v >= n) return;
    unsigned p = ptr[v], pe = ptr[v + 1];
    float a0 = 0.f, a1 = 0.f, a2 = 0.f, a3 = 0.f;
    for (; p + 4 <= pe; p += 4) {
        unsigned r0 = eb2[p], r1 = eb2[p + 1], r2 = eb2[p + 2], r3 = eb2[p + 3];
        a0 += bf2f(gb[(size_t)r0 * 16 + j]);
        a1 += bf2f(gb[(size_t)r1 * 16 + j]);
        a2 += bf2f(gb[(size_t)r2 * 16 + j]);
        a3 += bf2f(gb[(size_t)r3 * 16 + j]);
    }
    for (; p < pe; ++p) a0 += bf2f(gb[(size_t)eb2[p] * 16 + j]);
    float s = (a0 + a1) + (a2 + a3);
    float di = dinv[v];
    float val = di * (g[(size_t)v * 16 + j] + s) + b1[j];
    val = fmaxf(val, 0.f);
    float pr = val * W2[j];
    pr += __shfl_down(pr, 8, 16);
    pr += __shfl_down(pr, 4, 16);
    pr += __shfl_down(pr, 2, 16);
    pr += __shfl_down(pr, 1, 16);
    if (j == 0) g2[v] = pr * di;
}

// Layer-2 agg as CSR segmented reduction + fused output.
__global__ __launch_bounds__(256) void k_agg1f(const unsigned* __restrict__ ptr,
                                               const unsigned* __restrict__ eb2,
                                               const float* __restrict__ g2,
                                               const float* __restrict__ dinv,
                                               const float* __restrict__ b2,
                                               float* __restrict__ out, int n) {
    int tid = threadIdx.x;
    int grp = tid >> 4, j = tid & 15;
    int v = blockIdx.x * 16 + grp;
    if (v >= n) return;
    unsigned p0 = ptr[v], pe = ptr[v + 1];
    float a = 0.f;
    for (unsigned i = p0 + j; i < pe; i += 16) a += g2[eb2[i]];
    a += __shfl_down(a, 8, 16);
    a += __shfl_down(a, 4, 16);
    a += __shfl_down(a, 2, 16);
    a += __shfl_down(a, 1, 16);
    if (j == 0) out[v] = dinv[v] * (g2[v] + a) + b2[0];
}

extern "C" void kernel_launch(void* const* d_in, const int* in_sizes, int n_in,
                              void* d_out, int out_size, void* d_ws, size_t ws_size,
                              hipStream_t stream) {
    const float* x   = (const float*)d_in[0];
    const float* ea  = (const float*)d_in[1];
    const int*   row = (const int*)d_in[2];
    const int*   col = (const int*)d_in[3];
    const float* W1  = (const float*)d_in[4];
    const float* b1  = (const float*)d_in[5];
    const float* W2  = (const float*)d_in[6];
    const float* b2  = (const float*)d_in[7];
    float* out = (float*)d_out;

    int n  = in_sizes[0] / D_FEAT;   // 100000
    int ne = in_sizes[2];            // 6400000
    int nb = (n + 255) >> 8;         // 391 buckets of 256 nodes

    float* ws   = (float*)d_ws;
    float* xe   = ws;                      // n
    float* dinv = ws + (size_t)n;          // n
    float* g    = ws + (size_t)2 * n;      // 16n
    float* g2   = ws + (size_t)18 * n;     // n
    unsigned short* gbuf = (unsigned short*)(ws + (size_t)19 * n);  // 16n ushort = 8n floats
    unsigned* ptr     = (unsigned*)(ws + (size_t)27 * n);  // nb*256+1
    unsigned* gcnt    = ptr + (size_t)nb * 256 + 64;       // nb*16
    unsigned* gstart  = gcnt + (size_t)nb * 16;
    unsigned* gcursor = gstart + (size_t)nb * 16;
    unsigned* ebuf    = gcursor + (size_t)nb * 16;         // ne
    unsigned* ebuf2   = ebuf + (size_t)ne;                 // ne

    dim3 blk(256);
    int g_node = (n + 255) / 256;
    int g_tile = (ne + TILE - 1) / TILE;
    int g_gemm = (n + 63) / 64;
    int g_n16  = (n + 15) / 16;

    k_init<<<g_node, blk, 0, stream>>>(xe, gcnt, n, nb * 16);
    k_prep<<<g_tile, blk, 0, stream>>>(row, col, ea, xe, gcnt, ne, nb);
    k_scan<<<1, 512, 0, stream>>>(gcnt, gstart, gcursor, nb);
    k_place<<<g_tile, 512, 0, stream>>>(row, col, gcursor, ebuf, ne, nb);
    k_csr_scatter<<<nb, blk, 0, stream>>>(ebuf, gcnt, gstart, ptr, dinv, ebuf2, n, nb);
    k_gemm1<<<g_gemm, blk, 0, stream>>>(x, xe, dinv, W1, g, gbuf, n);
    k_agg16f<<<g_n16, blk, 0, stream>>>(ptr, ebuf2, gbuf, g, dinv, b1, W2, g2, n);
    k_agg1f<<<g_n16, blk, 0, stream>>>(ptr, ebuf2, g2, dinv, b2, out, n);
}

// Round 9
// 363.446 us; speedup vs baseline: 2.3550x; 1.0679x over previous
//
#include <hip/hip_runtime.h>

// GCN_88734024335852 — 2-layer GCN on MI355X
//
// R9: R8's CSR agg fixed the LDS-atomic bound (549->62us). Remaining ~326us
// is the sort pipeline's redundant passes. Padded-bucket counting sort:
// fixed CAP=17408 per bucket (mean 16384, sigma 128 -> never overflows) lets
// tiles claim regions from per-bucket global cursors directly — no count
// pass, no global scan. xe segmented scan fused into the same kernel.
// 8 kernels -> 6.
//
//   dinv[i] = rsqrt(deg_in[i]+1)
//   layer out[c] = dinv[c] * ( g[c] + sum_{col[e]==c} g[row[e]] ) + b
//   g[i] = (h[i] @ W) * dinv[i]
//
// ws (floats): xe[n] dinv[n] g[16n] g2[n] gbuf[8n] uptr[2n] gcur[nb*16]
//              ebufP[nb*CAP] ebuf2P[nb*CAP]   (~66 MB)

#define D_FEAT 128
#define HIDDEN 16
#define TILE 8192
#define CAP 17408u

__device__ inline float bf2f(unsigned short u) {
    union { unsigned x; float f; } t; t.x = ((unsigned)u) << 16; return t.f;
}

__global__ __launch_bounds__(256) void k_init(float* xe, unsigned* gcur, int n, int nb) {
    int t = blockIdx.x * 256 + threadIdx.x;
    if (t < n) xe[t] = 0.f;
    if (t < nb) gcur[t * 16] = (unsigned)t * CAP;
}

// Fused sort+scan: per 8192-edge tile: load row/col/ea; xe wave segmented
// scan (rows sorted); LDS bucket hist; claim padded-bucket regions from
// global cursors; stage bucket-ordered in LDS; coalesced run writes.
__global__ __launch_bounds__(512) void k_sortplace(const int* __restrict__ row,
                                                   const int* __restrict__ col,
                                                   const float* __restrict__ ea,
                                                   float* __restrict__ xe,
                                                   unsigned* __restrict__ gcur,
                                                   unsigned* __restrict__ ebufP,
                                                   int ne, int nb) {
    __shared__ unsigned stage[TILE];
    __shared__ unsigned short sbuck[TILE];
    __shared__ unsigned h[512], sc[512], base_[512], cursor[512], gb_[512];
    int tid = threadIdx.x;
    int lane = tid & 63;
    int tile0 = blockIdx.x * TILE;
    int cnt_t = min(TILE, ne - tile0);
    h[tid] = 0u;
    __syncthreads();
    int rr[16], cc[16];
    float aa[16];
    #pragma unroll
    for (int k = 0; k < 16; ++k) {
        int e = tile0 + tid + k * 512;
        if (e < ne) {
            rr[k] = row[e]; cc[k] = col[e]; aa[k] = ea[e];
            atomicAdd(&h[cc[k] >> 8], 1u);
        } else { rr[k] = -1; aa[k] = 0.f; }
    }
    // xe segmented scan per 64-edge wave window (rows sorted globally).
    #pragma unroll
    for (int k = 0; k < 16; ++k) {
        int r = rr[k];
        float a = aa[k];
        #pragma unroll
        for (int d = 1; d < 64; d <<= 1) {
            float up = __shfl_up(a, d);
            int  rup = __shfl_up(r, d);
            if (lane >= d && rup == r) a += up;
        }
        int rdn = __shfl_down(r, 1);
        bool tail = (lane == 63) || (rdn != r);
        if (r >= 0 && tail) unsafeAtomicAdd(&xe[r], a);
    }
    __syncthreads();
    sc[tid] = h[tid];
    __syncthreads();
    for (int off = 1; off < 512; off <<= 1) {
        unsigned u = (tid >= off) ? sc[tid - off] : 0u;
        __syncthreads();
        sc[tid] += u;
        __syncthreads();
    }
    unsigned ex = sc[tid] - h[tid];
    base_[tid] = ex;
    cursor[tid] = ex;
    if (tid < nb && h[tid]) gb_[tid] = atomicAdd(&gcur[tid * 16], h[tid]);
    __syncthreads();
    #pragma unroll
    for (int k = 0; k < 16; ++k) {
        if (rr[k] >= 0) {
            int b = cc[k] >> 8;
            unsigned p = atomicAdd(&cursor[b], 1u);
            stage[p] = (((unsigned)(cc[k] & 255)) << 24) | (unsigned)rr[k];
            sbuck[p] = (unsigned short)b;
        }
    }
    __syncthreads();
    for (int t = tid; t < cnt_t; t += 512) {
        unsigned b = sbuck[t];
        unsigned pos = gb_[b] + ((unsigned)t - base_[b]);
        if (pos < (b + 1u) * CAP) ebufP[pos] = stage[t];
    }
}

// Per bucket: exact-col histogram -> uptr{start,end} + dinv, scatter into
// col-sorted ebuf2P (within padded region).
__global__ __launch_bounds__(256) void k_csr2(const unsigned* __restrict__ ebufP,
                                              const unsigned* __restrict__ gcur,
                                              uint2* __restrict__ uptr,
                                              float* __restrict__ dinv,
                                              unsigned* __restrict__ ebuf2P,
                                              int n, int nb) {
    __shared__ unsigned dg[256], sc[256], cur[256];
    int b = blockIdx.x, tid = threadIdx.x;
    dg[tid] = 0u;
    __syncthreads();
    unsigned base = (unsigned)b * CAP;
    unsigned m = min(gcur[b * 16] - base, CAP);
    for (unsigned i = tid; i < m; i += 256) atomicAdd(&dg[ebufP[base + i] >> 24], 1u);
    __syncthreads();
    sc[tid] = dg[tid];
    __syncthreads();
    for (int off = 1; off < 256; off <<= 1) {
        unsigned u = (tid >= off) ? sc[tid - off] : 0u;
        __syncthreads();
        sc[tid] += u;
        __syncthreads();
    }
    unsigned ex = sc[tid] - dg[tid];
    int node = b * 256 + tid;
    if (node < n) {
        uptr[node] = make_uint2(base + ex, base + ex + dg[tid]);
        dinv[node] = rsqrtf((float)dg[tid] + 1.0f);
    }
    cur[tid] = base + ex;
    __syncthreads();
    unsigned i = tid;
    for (; i + 768 < m; i += 1024) {
        unsigned pk0 = ebufP[base + i];
        unsigned pk1 = ebufP[base + i + 256];
        unsigned pk2 = ebufP[base + i + 512];
        unsigned pk3 = ebufP[base + i + 768];
        unsigned p0 = atomicAdd(&cur[pk0 >> 24], 1u);
        unsigned p1 = atomicAdd(&cur[pk1 >> 24], 1u);
        unsigned p2 = atomicAdd(&cur[pk2 >> 24], 1u);
        unsigned p3 = atomicAdd(&cur[pk3 >> 24], 1u);
        ebuf2P[p0] = pk0 & 0xFFFFFFu;
        ebuf2P[p1] = pk1 & 0xFFFFFFu;
        ebuf2P[p2] = pk2 & 0xFFFFFFu;
        ebuf2P[p3] = pk3 & 0xFFFFFFu;
    }
    for (; i < m; i += 256) {
        unsigned pk = ebufP[base + i];
        unsigned p = atomicAdd(&cur[pk >> 24], 1u);
        ebuf2P[p] = pk & 0xFFFFFFu;
    }
}

// g[i][j] = (sum_k x[i][k]*W1[k][j] + xe[i]*W1[128][j]) * dinv[i]
// Writes fp32 g (self-term) and bf16 gbuf (gather copy, RNE).
__global__ __launch_bounds__(256) void k_gemm1(const float* __restrict__ x,
                                               const float* __restrict__ xe,
                                               const float* __restrict__ dinv,
                                               const float* __restrict__ W1,
                                               float* __restrict__ g,
                                               unsigned short* __restrict__ gb, int n) {
    __shared__ float Ws[129 * 16];
    __shared__ float xs[64 * 132];
    int tid = threadIdx.x;
    for (int idx = tid; idx < 129 * 16; idx += 256) Ws[idx] = W1[idx];
    int n0 = blockIdx.x * 64;
    const float4* x4 = (const float4*)x;
    for (int idx = tid; idx < 64 * 32; idx += 256) {
        int r = idx >> 5, c = idx & 31;
        float4 v = (n0 + r < n) ? x4[(size_t)(n0 + r) * 32 + c]
                                : make_float4(0.f, 0.f, 0.f, 0.f);
        *(float4*)&xs[r * 132 + c * 4] = v;
    }
    if (tid < 64) {
        int r = tid;
        xs[r * 132 + 128] = (n0 + r < n) ? xe[n0 + r] : 0.f;
    }
    __syncthreads();
    int j  = tid & 15;
    int nb = tid >> 4;
    for (int rep = 0; rep < 4; ++rep) {
        int nl = nb + (rep << 4);
        int node = n0 + nl;
        const float* xrow = &xs[nl * 132];
        float acc = 0.f;
        #pragma unroll
        for (int k = 0; k < 128; k += 4) {
            float4 xv = *(const float4*)&xrow[k];
            acc += xv.x * Ws[(k + 0) * 16 + j];
            acc += xv.y * Ws[(k + 1) * 16 + j];
            acc += xv.z * Ws[(k + 2) * 16 + j];
            acc += xv.w * Ws[(k + 3) * 16 + j];
        }
        acc += xrow[128] * Ws[128 * 16 + j];
        if (node < n) {
            float v = acc * dinv[node];
            g[(size_t)node * 16 + j] = v;
            union { float f; unsigned u; } cv; cv.f = v;
            unsigned r16 = (cv.u + 0x7FFFu + ((cv.u >> 16) & 1u)) >> 16;
            gb[(size_t)node * 16 + j] = (unsigned short)r16;
        }
    }
}

// Layer-1 agg as CSR segmented reduction + fused epilogue.
// 16 lanes per node; lane j owns feature j. No LDS, no atomics.
__global__ __launch_bounds__(256) void k_agg16f(const uint2* __restrict__ uptr,
                                                const unsigned* __restrict__ eb2,
                                                const unsigned short* __restrict__ gb,
                                                const float* __restrict__ g,
                                                const float* __restrict__ dinv,
                                                const float* __restrict__ b1,
                                                const float* __restrict__ W2,
                                                float* __restrict__ g2, int n) {
    int tid = threadIdx.x;
    int grp = tid >> 4, j = tid & 15;
    int v = blockIdx.x * 16 + grp;
    if (v >= n) return;
    uint2 pr = uptr[v];
    unsigned p = pr.x, pe = pr.y;
    float a0 = 0.f, a1 = 0.f, a2 = 0.f, a3 = 0.f;
    for (; p + 4 <= pe; p += 4) {
        unsigned r0 = eb2[p], r1 = eb2[p + 1], r2 = eb2[p + 2], r3 = eb2[p + 3];
        a0 += bf2f(gb[(size_t)r0 * 16 + j]);
        a1 += bf2f(gb[(size_t)r1 * 16 + j]);
        a2 += bf2f(gb[(size_t)r2 * 16 + j]);
        a3 += bf2f(gb[(size_t)r3 * 16 + j]);
    }
    for (; p < pe; ++p) a0 += bf2f(gb[(size_t)eb2[p] * 16 + j]);
    float s = (a0 + a1) + (a2 + a3);
    float di = dinv[v];
    float val = di * (g[(size_t)v * 16 + j] + s) + b1[j];
    val = fmaxf(val, 0.f);
    float prd = val * W2[j];
    prd += __shfl_down(prd, 8, 16);
    prd += __shfl_down(prd, 4, 16);
    prd += __shfl_down(prd, 2, 16);
    prd += __shfl_down(prd, 1, 16);
    if (j == 0) g2[v] = prd * di;
}

// Layer-2 agg as CSR segmented reduction + fused output.
__global__ __launch_bounds__(256) void k_agg1f(const uint2* __restrict__ uptr,
                                               const unsigned* __restrict__ eb2,
                                               const float* __restrict__ g2,
                                               const float* __restrict__ dinv,
                                               const float* __restrict__ b2,
                                               float* __restrict__ out, int n) {
    int tid = threadIdx.x;
    int grp = tid >> 4, j = tid & 15;
    int v = blockIdx.x * 16 + grp;
    if (v >= n) return;
    uint2 pr = uptr[v];
    float a = 0.f;
    for (unsigned i = pr.x + j; i < pr.y; i += 16) a += g2[eb2[i]];
    a += __shfl_down(a, 8, 16);
    a += __shfl_down(a, 4, 16);
    a += __shfl_down(a, 2, 16);
    a += __shfl_down(a, 1, 16);
    if (j == 0) out[v] = dinv[v] * (g2[v] + a) + b2[0];
}

extern "C" void kernel_launch(void* const* d_in, const int* in_sizes, int n_in,
                              void* d_out, int out_size, void* d_ws, size_t ws_size,
                              hipStream_t stream) {
    const float* x   = (const float*)d_in[0];
    const float* ea  = (const float*)d_in[1];
    const int*   row = (const int*)d_in[2];
    const int*   col = (const int*)d_in[3];
    const float* W1  = (const float*)d_in[4];
    const float* b1  = (const float*)d_in[5];
    const float* W2  = (const float*)d_in[6];
    const float* b2  = (const float*)d_in[7];
    float* out = (float*)d_out;

    int n  = in_sizes[0] / D_FEAT;   // 100000
    int ne = in_sizes[2];            // 6400000
    int nb = (n + 255) >> 8;         // 391 buckets of 256 nodes

    float* ws   = (float*)d_ws;
    float* xe   = ws;                      // n
    float* dinv = ws + (size_t)n;          // n
    float* g    = ws + (size_t)2 * n;      // 16n
    float* g2   = ws + (size_t)18 * n;     // n
    unsigned short* gbuf = (unsigned short*)(ws + (size_t)19 * n);  // 16n ushort = 8n floats
    uint2*    uptr  = (uint2*)(ws + (size_t)27 * n);       // n uint2 = 2n
    unsigned* gcur  = (unsigned*)(ws + (size_t)29 * n);    // nb*16
    unsigned* ebufP  = gcur + (size_t)nb * 16;             // nb*CAP
    unsigned* ebuf2P = ebufP + (size_t)nb * CAP;           // nb*CAP

    dim3 blk(256);
    int g_node = (n + 255) / 256;
    int g_tile = (ne + TILE - 1) / TILE;
    int g_gemm = (n + 63) / 64;
    int g_n16  = (n + 15) / 16;

    k_init<<<g_node, blk, 0, stream>>>(xe, gcur, n, nb);
    k_sortplace<<<g_tile, 512, 0, stream>>>(row, col, ea, xe, gcur, ebufP, ne, nb);
    k_csr2<<<nb, blk, 0, stream>>>(ebufP, gcur, uptr, dinv, ebuf2P, n, nb);
    k_gemm1<<<g_gemm, blk, 0, stream>>>(x, xe, dinv, W1, g, gbuf, n);
    k_agg16f<<<g_n16, blk, 0, stream>>>(uptr, ebuf2P, gbuf, g, dinv, b1, W2, g2, n);
    k_agg1f<<<g_n16, blk, 0, stream>>>(uptr, ebuf2P, g2, dinv, b2, out, n);
}

// Round 10
// 354.897 us; speedup vs baseline: 2.4117x; 1.0241x over previous
//
#include <hip/hip_runtime.h>

// GCN_88734024335852 — 2-layer GCN on MI355X
//
// R10: (1) sortplace: drop LDS staging+scan (59KB LDS -> 31% occ, 2.0M bank
// conflicts); hist -> claim bucket region -> direct global 4B scatter via
// LDS cursors (L2 merges lines; R5 showed region writes coalesce fine).
// (2) csr2 at 1024 thr/block (391 blocks were latency-starved at 256).
// (3) agg16: packed uint gathers (2 bf16/lane, 8 lanes/edge, even/odd edge
// halves + shfl_xor combine) -> half the memory lane-ops per edge.
//
//   dinv[i] = rsqrt(deg_in[i]+1)
//   layer out[c] = dinv[c] * ( g[c] + sum_{col[e]==c} g[row[e]] ) + b
//   g[i] = (h[i] @ W) * dinv[i]
//
// ws (floats): xe[n] dinv[n] g[16n] g2[n] gbuf[8n] uptr[2n] gcur[nb*16]
//              ebufP[nb*CAP] ebuf2P[nb*CAP]   (~66 MB, same as R9)

#define D_FEAT 128
#define HIDDEN 16
#define TILE 8192
#define CAP 17408u

__device__ inline float bf2f(unsigned short u) {
    union { unsigned x; float f; } t; t.x = ((unsigned)u) << 16; return t.f;
}

__global__ __launch_bounds__(256) void k_init(float* xe, unsigned* gcur, int n, int nb) {
    int t = blockIdx.x * 256 + threadIdx.x;
    if (t < n) xe[t] = 0.f;
    if (t < nb) gcur[t * 16] = (unsigned)t * CAP;
}

// Fused: load row/col/ea; xe wave segmented scan (rows sorted); LDS bucket
// hist; claim padded-bucket regions; direct global scatter via LDS cursors.
__global__ __launch_bounds__(512) void k_sortplace(const int* __restrict__ row,
                                                   const int* __restrict__ col,
                                                   const float* __restrict__ ea,
                                                   float* __restrict__ xe,
                                                   unsigned* __restrict__ gcur,
                                                   unsigned* __restrict__ ebufP,
                                                   int ne, int nb) {
    __shared__ unsigned h[512], cursor[512];
    int tid = threadIdx.x;
    int lane = tid & 63;
    int tile0 = blockIdx.x * TILE;
    h[tid] = 0u;
    __syncthreads();
    int rr[16], cc[16];
    float aa[16];
    #pragma unroll
    for (int k = 0; k < 16; ++k) {
        int e = tile0 + tid + k * 512;
        if (e < ne) {
            rr[k] = row[e]; cc[k] = col[e]; aa[k] = ea[e];
            atomicAdd(&h[cc[k] >> 8], 1u);
        } else { rr[k] = -1; cc[k] = 0; aa[k] = 0.f; }
    }
    // xe segmented scan per 64-edge wave window (rows sorted globally).
    #pragma unroll
    for (int k = 0; k < 16; ++k) {
        int r = rr[k];
        float a = aa[k];
        #pragma unroll
        for (int d = 1; d < 64; d <<= 1) {
            float up = __shfl_up(a, d);
            int  rup = __shfl_up(r, d);
            if (lane >= d && rup == r) a += up;
        }
        int rdn = __shfl_down(r, 1);
        bool tail = (lane == 63) || (rdn != r);
        if (r >= 0 && tail) unsafeAtomicAdd(&xe[r], a);
    }
    __syncthreads();
    if (tid < nb && h[tid]) cursor[tid] = atomicAdd(&gcur[tid * 16], h[tid]);
    __syncthreads();
    #pragma unroll
    for (int k = 0; k < 16; ++k) {
        if (rr[k] >= 0) {
            int b = cc[k] >> 8;
            unsigned pos = atomicAdd(&cursor[b], 1u);
            if (pos < (unsigned)(b + 1) * CAP)
                ebufP[pos] = (((unsigned)(cc[k] & 255)) << 24) | (unsigned)rr[k];
        }
    }
}

// Per bucket (1024 threads): exact-col histogram -> uptr{start,end} + dinv,
// scatter into col-sorted ebuf2P.
__global__ __launch_bounds__(1024) void k_csr2(const unsigned* __restrict__ ebufP,
                                               const unsigned* __restrict__ gcur,
                                               uint2* __restrict__ uptr,
                                               float* __restrict__ dinv,
                                               unsigned* __restrict__ ebuf2P,
                                               int n, int nb) {
    __shared__ unsigned dg[256], sc[256], cur[256];
    int b = blockIdx.x, tid = threadIdx.x;
    if (tid < 256) dg[tid] = 0u;
    __syncthreads();
    unsigned base = (unsigned)b * CAP;
    unsigned m = min(gcur[b * 16] - base, CAP);
    for (unsigned i = tid; i < m; i += 1024) atomicAdd(&dg[ebufP[base + i] >> 24], 1u);
    __syncthreads();
    if (tid < 256) sc[tid] = dg[tid];
    __syncthreads();
    for (int off = 1; off < 256; off <<= 1) {
        unsigned u = 0;
        if (tid < 256 && tid >= off) u = sc[tid - off];
        __syncthreads();
        if (tid < 256) sc[tid] += u;
        __syncthreads();
    }
    if (tid < 256) {
        unsigned ex = sc[tid] - dg[tid];
        int node = b * 256 + tid;
        if (node < n) {
            uptr[node] = make_uint2(base + ex, base + ex + dg[tid]);
            dinv[node] = rsqrtf((float)dg[tid] + 1.0f);
        }
        cur[tid] = base + ex;
    }
    __syncthreads();
    unsigned i = tid;
    for (; i + 3072 < m; i += 4096) {
        unsigned pk0 = ebufP[base + i];
        unsigned pk1 = ebufP[base + i + 1024];
        unsigned pk2 = ebufP[base + i + 2048];
        unsigned pk3 = ebufP[base + i + 3072];
        unsigned p0 = atomicAdd(&cur[pk0 >> 24], 1u);
        unsigned p1 = atomicAdd(&cur[pk1 >> 24], 1u);
        unsigned p2 = atomicAdd(&cur[pk2 >> 24], 1u);
        unsigned p3 = atomicAdd(&cur[pk3 >> 24], 1u);
        ebuf2P[p0] = pk0 & 0xFFFFFFu;
        ebuf2P[p1] = pk1 & 0xFFFFFFu;
        ebuf2P[p2] = pk2 & 0xFFFFFFu;
        ebuf2P[p3] = pk3 & 0xFFFFFFu;
    }
    for (; i < m; i += 1024) {
        unsigned pk = ebufP[base + i];
        unsigned p = atomicAdd(&cur[pk >> 24], 1u);
        ebuf2P[p] = pk & 0xFFFFFFu;
    }
}

// g[i][j] = (sum_k x[i][k]*W1[k][j] + xe[i]*W1[128][j]) * dinv[i]
// Writes fp32 g (self-term) and bf16 gbuf (gather copy, RNE).
__global__ __launch_bounds__(256) void k_gemm1(const float* __restrict__ x,
                                               const float* __restrict__ xe,
                                               const float* __restrict__ dinv,
                                               const float* __restrict__ W1,
                                               float* __restrict__ g,
                                               unsigned short* __restrict__ gb, int n) {
    __shared__ float Ws[129 * 16];
    __shared__ float xs[64 * 132];
    int tid = threadIdx.x;
    for (int idx = tid; idx < 129 * 16; idx += 256) Ws[idx] = W1[idx];
    int n0 = blockIdx.x * 64;
    const float4* x4 = (const float4*)x;
    for (int idx = tid; idx < 64 * 32; idx += 256) {
        int r = idx >> 5, c = idx & 31;
        float4 v = (n0 + r < n) ? x4[(size_t)(n0 + r) * 32 + c]
                                : make_float4(0.f, 0.f, 0.f, 0.f);
        *(float4*)&xs[r * 132 + c * 4] = v;
    }
    if (tid < 64) {
        int r = tid;
        xs[r * 132 + 128] = (n0 + r < n) ? xe[n0 + r] : 0.f;
    }
    __syncthreads();
    int j  = tid & 15;
    int nb = tid >> 4;
    for (int rep = 0; rep < 4; ++rep) {
        int nl = nb + (rep << 4);
        int node = n0 + nl;
        const float* xrow = &xs[nl * 132];
        float acc = 0.f;
        #pragma unroll
        for (int k = 0; k < 128; k += 4) {
            float4 xv = *(const float4*)&xrow[k];
            acc += xv.x * Ws[(k + 0) * 16 + j];
            acc += xv.y * Ws[(k + 1) * 16 + j];
            acc += xv.z * Ws[(k + 2) * 16 + j];
            acc += xv.w * Ws[(k + 3) * 16 + j];
        }
        acc += xrow[128] * Ws[128 * 16 + j];
        if (node < n) {
            float v = acc * dinv[node];
            g[(size_t)node * 16 + j] = v;
            union { float f; unsigned u; } cv; cv.f = v;
            unsigned r16 = (cv.u + 0x7FFFu + ((cv.u >> 16) & 1u)) >> 16;
            gb[(size_t)node * 16 + j] = (unsigned short)r16;
        }
    }
}

// Layer-1 agg, packed: 16 lanes/node; lane u=tid&7 owns feature pair
// (2u,2u+1) as one uint load; halves (tid>>3)&1 split even/odd edges;
// shfl_xor(8) combines. Fused epilogue. No LDS, no atomics.
__global__ __launch_bounds__(256) void k_agg16g(const uint2* __restrict__ uptr,
                                                const unsigned* __restrict__ eb2,
                                                const unsigned* __restrict__ gu,
                                                const float* __restrict__ g,
                                                const float* __restrict__ dinv,
                                                const float* __restrict__ b1,
                                                const float* __restrict__ W2,
                                                float* __restrict__ g2, int n) {
    int tid = threadIdx.x;
    int grp = tid >> 4, j16 = tid & 15;
    int u = tid & 7;
    int half = (tid >> 3) & 1;
    int v = blockIdx.x * 16 + grp;
    if (v >= n) return;
    uint2 pr = uptr[v];
    float ax0 = 0.f, ay0 = 0.f, ax1 = 0.f, ay1 = 0.f;
    unsigned q = pr.x + half;
    for (; q + 2 < pr.y; q += 4) {
        unsigned r0 = eb2[q], r1 = eb2[q + 2];
        unsigned w0 = gu[(size_t)r0 * 8 + u];
        unsigned w1 = gu[(size_t)r1 * 8 + u];
        ax0 += bf2f((unsigned short)w0); ay0 += bf2f((unsigned short)(w0 >> 16));
        ax1 += bf2f((unsigned short)w1); ay1 += bf2f((unsigned short)(w1 >> 16));
    }
    if (q < pr.y) {
        unsigned w = gu[(size_t)eb2[q] * 8 + u];
        ax0 += bf2f((unsigned short)w); ay0 += bf2f((unsigned short)(w >> 16));
    }
    float sx = ax0 + ax1, sy = ay0 + ay1;
    sx += __shfl_xor(sx, 8, 16);
    sy += __shfl_xor(sy, 8, 16);
    float di = dinv[v];
    float2 gs = ((const float2*)g)[(size_t)v * 8 + u];
    float2 bb = ((const float2*)b1)[u];
    float2 ww = ((const float2*)W2)[u];
    float vx = fmaxf(di * (gs.x + sx) + bb.x, 0.f);
    float vy = fmaxf(di * (gs.y + sy) + bb.y, 0.f);
    float prd = vx * ww.x + vy * ww.y;
    prd += __shfl_down(prd, 4, 8);
    prd += __shfl_down(prd, 2, 8);
    prd += __shfl_down(prd, 1, 8);
    if (j16 == 0) g2[v] = prd * di;
}

// Layer-2 agg as CSR segmented reduction + fused output.
__global__ __launch_bounds__(256) void k_agg1f(const uint2* __restrict__ uptr,
                                               const unsigned* __restrict__ eb2,
                                               const float* __restrict__ g2,
                                               const float* __restrict__ dinv,
                                               const float* __restrict__ b2,
                                               float* __restrict__ out, int n) {
    int tid = threadIdx.x;
    int grp = tid >> 4, j = tid & 15;
    int v = blockIdx.x * 16 + grp;
    if (v >= n) return;
    uint2 pr = uptr[v];
    float a = 0.f;
    for (unsigned i = pr.x + j; i < pr.y; i += 16) a += g2[eb2[i]];
    a += __shfl_down(a, 8, 16);
    a += __shfl_down(a, 4, 16);
    a += __shfl_down(a, 2, 16);
    a += __shfl_down(a, 1, 16);
    if (j == 0) out[v] = dinv[v] * (g2[v] + a) + b2[0];
}

extern "C" void kernel_launch(void* const* d_in, const int* in_sizes, int n_in,
                              void* d_out, int out_size, void* d_ws, size_t ws_size,
                              hipStream_t stream) {
    const float* x   = (const float*)d_in[0];
    const float* ea  = (const float*)d_in[1];
    const int*   row = (const int*)d_in[2];
    const int*   col = (const int*)d_in[3];
    const float* W1  = (const float*)d_in[4];
    const float* b1  = (const float*)d_in[5];
    const float* W2  = (const float*)d_in[6];
    const float* b2  = (const float*)d_in[7];
    float* out = (float*)d_out;

    int n  = in_sizes[0] / D_FEAT;   // 100000
    int ne = in_sizes[2];            // 6400000
    int nb = (n + 255) >> 8;         // 391 buckets of 256 nodes

    float* ws   = (float*)d_ws;
    float* xe   = ws;                      // n
    float* dinv = ws + (size_t)n;          // n
    float* g    = ws + (size_t)2 * n;      // 16n
    float* g2   = ws + (size_t)18 * n;     // n
    unsigned short* gbuf = (unsigned short*)(ws + (size_t)19 * n);  // 16n ushort = 8n floats
    uint2*    uptr  = (uint2*)(ws + (size_t)27 * n);       // n uint2 = 2n
    unsigned* gcur  = (unsigned*)(ws + (size_t)29 * n);    // nb*16
    unsigned* ebufP  = gcur + (size_t)nb * 16;             // nb*CAP
    unsigned* ebuf2P = ebufP + (size_t)nb * CAP;           // nb*CAP

    dim3 blk(256);
    int g_node = (n + 255) / 256;
    int g_tile = (ne + TILE - 1) / TILE;
    int g_gemm = (n + 63) / 64;
    int g_n16  = (n + 15) / 16;

    k_init<<<g_node, blk, 0, stream>>>(xe, gcur, n, nb);
    k_sortplace<<<g_tile, 512, 0, stream>>>(row, col, ea, xe, gcur, ebufP, ne, nb);
    k_csr2<<<nb, 1024, 0, stream>>>(ebufP, gcur, uptr, dinv, ebuf2P, n, nb);
    k_gemm1<<<g_gemm, blk, 0, stream>>>(x, xe, dinv, W1, g, gbuf, n);
    k_agg16g<<<g_n16, blk, 0, stream>>>(uptr, ebuf2P, (const unsigned*)gbuf, g, dinv, b1, W2, g2, n);
    k_agg1f<<<g_n16, blk, 0, stream>>>(uptr, ebuf2P, g2, dinv, b2, out, n);
}

// Round 11
// 345.267 us; speedup vs baseline: 2.4790x; 1.0279x over previous
//
#include <hip/hip_runtime.h>

// GCN_88734024335852 — 2-layer GCN on MI355X
//
// R11: R10 showed sortplace's LDS staging earned its cost (direct 4B scatter:
// 69->77us, WRITE 44->55MB) and occupancy wasn't the limiter. Restore staged
// sort at TILE=4096 (34KB LDS -> 4 blocks/CU, full occupancy AND coalesced
// writes). gemm1: transposed W in LDS (WsT[j][k], stride 132) -> weight
// reads become ds_read_b128 (160->64 LDS instrs per rep).
//
//   dinv[i] = rsqrt(deg_in[i]+1)
//   layer out[c] = dinv[c] * ( g[c] + sum_{col[e]==c} g[row[e]] ) + b
//   g[i] = (h[i] @ W) * dinv[i]
//
// ws (floats): xe[n] dinv[n] g[16n] g2[n] gbuf[8n] uptr[2n] gcur[nb*16]
//              ebufP[nb*CAP] ebuf2P[nb*CAP]   (~66 MB)

#define D_FEAT 128
#define HIDDEN 16
#define TILE 4096
#define CAP 17408u

__device__ inline float bf2f(unsigned short u) {
    union { unsigned x; float f; } t; t.x = ((unsigned)u) << 16; return t.f;
}

__global__ __launch_bounds__(256) void k_init(float* xe, unsigned* gcur, int n, int nb) {
    int t = blockIdx.x * 256 + threadIdx.x;
    if (t < n) xe[t] = 0.f;
    if (t < nb) gcur[t * 16] = (unsigned)t * CAP;
}

// Fused: load row/col/ea; xe wave segmented scan (rows sorted); LDS bucket
// hist; block scan; claim padded-bucket regions; stage bucket-ordered in
// LDS; coalesced run writes.
__global__ __launch_bounds__(512) void k_sortplace(const int* __restrict__ row,
                                                   const int* __restrict__ col,
                                                   const float* __restrict__ ea,
                                                   float* __restrict__ xe,
                                                   unsigned* __restrict__ gcur,
                                                   unsigned* __restrict__ ebufP,
                                                   int ne, int nb) {
    __shared__ unsigned stage[TILE];
    __shared__ unsigned short sbuck[TILE];
    __shared__ unsigned h[512], sc[512], base_[512], cursor[512], gb_[512];
    int tid = threadIdx.x;
    int lane = tid & 63;
    int tile0 = blockIdx.x * TILE;
    int cnt_t = min(TILE, ne - tile0);
    h[tid] = 0u;
    __syncthreads();
    int rr[8], cc[8];
    float aa[8];
    #pragma unroll
    for (int k = 0; k < 8; ++k) {
        int e = tile0 + tid + k * 512;
        if (e < ne) {
            rr[k] = row[e]; cc[k] = col[e]; aa[k] = ea[e];
            atomicAdd(&h[cc[k] >> 8], 1u);
        } else { rr[k] = -1; cc[k] = 0; aa[k] = 0.f; }
    }
    // xe segmented scan per 64-edge wave window (rows sorted globally).
    #pragma unroll
    for (int k = 0; k < 8; ++k) {
        int r = rr[k];
        float a = aa[k];
        #pragma unroll
        for (int d = 1; d < 64; d <<= 1) {
            float up = __shfl_up(a, d);
            int  rup = __shfl_up(r, d);
            if (lane >= d && rup == r) a += up;
        }
        int rdn = __shfl_down(r, 1);
        bool tail = (lane == 63) || (rdn != r);
        if (r >= 0 && tail) unsafeAtomicAdd(&xe[r], a);
    }
    __syncthreads();
    sc[tid] = h[tid];
    __syncthreads();
    for (int off = 1; off < 512; off <<= 1) {
        unsigned u = (tid >= off) ? sc[tid - off] : 0u;
        __syncthreads();
        sc[tid] += u;
        __syncthreads();
    }
    unsigned ex = sc[tid] - h[tid];
    base_[tid] = ex;
    cursor[tid] = ex;
    if (tid < nb && h[tid]) gb_[tid] = atomicAdd(&gcur[tid * 16], h[tid]);
    __syncthreads();
    #pragma unroll
    for (int k = 0; k < 8; ++k) {
        if (rr[k] >= 0) {
            int b = cc[k] >> 8;
            unsigned p = atomicAdd(&cursor[b], 1u);
            stage[p] = (((unsigned)(cc[k] & 255)) << 24) | (unsigned)rr[k];
            sbuck[p] = (unsigned short)b;
        }
    }
    __syncthreads();
    for (int t = tid; t < cnt_t; t += 512) {
        unsigned b = sbuck[t];
        unsigned pos = gb_[b] + ((unsigned)t - base_[b]);
        if (pos < (b + 1u) * CAP) ebufP[pos] = stage[t];
    }
}

// Per bucket (1024 threads): exact-col histogram -> uptr{start,end} + dinv,
// scatter into col-sorted ebuf2P.
__global__ __launch_bounds__(1024) void k_csr2(const unsigned* __restrict__ ebufP,
                                               const unsigned* __restrict__ gcur,
                                               uint2* __restrict__ uptr,
                                               float* __restrict__ dinv,
                                               unsigned* __restrict__ ebuf2P,
                                               int n, int nb) {
    __shared__ unsigned dg[256], sc[256], cur[256];
    int b = blockIdx.x, tid = threadIdx.x;
    if (tid < 256) dg[tid] = 0u;
    __syncthreads();
    unsigned base = (unsigned)b * CAP;
    unsigned m = min(gcur[b * 16] - base, CAP);
    for (unsigned i = tid; i < m; i += 1024) atomicAdd(&dg[ebufP[base + i] >> 24], 1u);
    __syncthreads();
    if (tid < 256) sc[tid] = dg[tid];
    __syncthreads();
    for (int off = 1; off < 256; off <<= 1) {
        unsigned u = 0;
        if (tid < 256 && tid >= off) u = sc[tid - off];
        __syncthreads();
        if (tid < 256) sc[tid] += u;
        __syncthreads();
    }
    if (tid < 256) {
        unsigned ex = sc[tid] - dg[tid];
        int node = b * 256 + tid;
        if (node < n) {
            uptr[node] = make_uint2(base + ex, base + ex + dg[tid]);
            dinv[node] = rsqrtf((float)dg[tid] + 1.0f);
        }
        cur[tid] = base + ex;
    }
    __syncthreads();
    unsigned i = tid;
    for (; i + 3072 < m; i += 4096) {
        unsigned pk0 = ebufP[base + i];
        unsigned pk1 = ebufP[base + i + 1024];
        unsigned pk2 = ebufP[base + i + 2048];
        unsigned pk3 = ebufP[base + i + 3072];
        unsigned p0 = atomicAdd(&cur[pk0 >> 24], 1u);
        unsigned p1 = atomicAdd(&cur[pk1 >> 24], 1u);
        unsigned p2 = atomicAdd(&cur[pk2 >> 24], 1u);
        unsigned p3 = atomicAdd(&cur[pk3 >> 24], 1u);
        ebuf2P[p0] = pk0 & 0xFFFFFFu;
        ebuf2P[p1] = pk1 & 0xFFFFFFu;
        ebuf2P[p2] = pk2 & 0xFFFFFFu;
        ebuf2P[p3] = pk3 & 0xFFFFFFu;
    }
    for (; i < m; i += 1024) {
        unsigned pk = ebufP[base + i];
        unsigned p = atomicAdd(&cur[pk >> 24], 1u);
        ebuf2P[p] = pk & 0xFFFFFFu;
    }
}

// g[i][j] = (sum_k x[i][k]*W1[k][j] + xe[i]*W1[128][j]) * dinv[i]
// W transposed in LDS (stride 132) -> b128 weight reads.
// Writes fp32 g (self-term) and bf16 gbuf (gather copy, RNE).
__global__ __launch_bounds__(256) void k_gemm1(const float* __restrict__ x,
                                               const float* __restrict__ xe,
                                               const float* __restrict__ dinv,
                                               const float* __restrict__ W1,
                                               float* __restrict__ g,
                                               unsigned short* __restrict__ gb, int n) {
    __shared__ float WsT[16 * 132];   // WsT[j*132 + k] = W1[k*16 + j], k=0..128
    __shared__ float xs[64 * 132];
    int tid = threadIdx.x;
    for (int idx = tid; idx < 129 * 16; idx += 256) {
        int k = idx >> 4, j = idx & 15;
        WsT[j * 132 + k] = W1[idx];
    }
    int n0 = blockIdx.x * 64;
    const float4* x4 = (const float4*)x;
    for (int idx = tid; idx < 64 * 32; idx += 256) {
        int r = idx >> 5, c = idx & 31;
        float4 v = (n0 + r < n) ? x4[(size_t)(n0 + r) * 32 + c]
                                : make_float4(0.f, 0.f, 0.f, 0.f);
        *(float4*)&xs[r * 132 + c * 4] = v;
    }
    if (tid < 64) {
        int r = tid;
        xs[r * 132 + 128] = (n0 + r < n) ? xe[n0 + r] : 0.f;
    }
    __syncthreads();
    int j  = tid & 15;
    int nb = tid >> 4;
    const float* wrow = &WsT[j * 132];
    for (int rep = 0; rep < 4; ++rep) {
        int nl = nb + (rep << 4);
        int node = n0 + nl;
        const float* xrow = &xs[nl * 132];
        float acc = 0.f;
        #pragma unroll
        for (int k = 0; k < 128; k += 4) {
            float4 xv = *(const float4*)&xrow[k];
            float4 wv = *(const float4*)&wrow[k];
            acc += xv.x * wv.x;
            acc += xv.y * wv.y;
            acc += xv.z * wv.z;
            acc += xv.w * wv.w;
        }
        acc += xrow[128] * wrow[128];
        if (node < n) {
            float v = acc * dinv[node];
            g[(size_t)node * 16 + j] = v;
            union { float f; unsigned u; } cv; cv.f = v;
            unsigned r16 = (cv.u + 0x7FFFu + ((cv.u >> 16) & 1u)) >> 16;
            gb[(size_t)node * 16 + j] = (unsigned short)r16;
        }
    }
}

// Layer-1 agg, packed: 16 lanes/node; lane u=tid&7 owns feature pair
// (2u,2u+1) as one uint load; halves (tid>>3)&1 split even/odd edges;
// shfl_xor(8) combines. Fused epilogue. No LDS, no atomics.
__global__ __launch_bounds__(256) void k_agg16g(const uint2* __restrict__ uptr,
                                                const unsigned* __restrict__ eb2,
                                                const unsigned* __restrict__ gu,
                                                const float* __restrict__ g,
                                                const float* __restrict__ dinv,
                                                const float* __restrict__ b1,
                                                const float* __restrict__ W2,
                                                float* __restrict__ g2, int n) {
    int tid = threadIdx.x;
    int grp = tid >> 4, j16 = tid & 15;
    int u = tid & 7;
    int half = (tid >> 3) & 1;
    int v = blockIdx.x * 16 + grp;
    if (v >= n) return;
    uint2 pr = uptr[v];
    float ax0 = 0.f, ay0 = 0.f, ax1 = 0.f, ay1 = 0.f;
    unsigned q = pr.x + half;
    for (; q + 2 < pr.y; q += 4) {
        unsigned r0 = eb2[q], r1 = eb2[q + 2];
        unsigned w0 = gu[(size_t)r0 * 8 + u];
        unsigned w1 = gu[(size_t)r1 * 8 + u];
        ax0 += bf2f((unsigned short)w0); ay0 += bf2f((unsigned short)(w0 >> 16));
        ax1 += bf2f((unsigned short)w1); ay1 += bf2f((unsigned short)(w1 >> 16));
    }
    if (q < pr.y) {
        unsigned w = gu[(size_t)eb2[q] * 8 + u];
        ax0 += bf2f((unsigned short)w); ay0 += bf2f((unsigned short)(w >> 16));
    }
    float sx = ax0 + ax1, sy = ay0 + ay1;
    sx += __shfl_xor(sx, 8, 16);
    sy += __shfl_xor(sy, 8, 16);
    float di = dinv[v];
    float2 gs = ((const float2*)g)[(size_t)v * 8 + u];
    float2 bb = ((const float2*)b1)[u];
    float2 ww = ((const float2*)W2)[u];
    float vx = fmaxf(di * (gs.x + sx) + bb.x, 0.f);
    float vy = fmaxf(di * (gs.y + sy) + bb.y, 0.f);
    float prd = vx * ww.x + vy * ww.y;
    prd += __shfl_down(prd, 4, 8);
    prd += __shfl_down(prd, 2, 8);
    prd += __shfl_down(prd, 1, 8);
    if (j16 == 0) g2[v] = prd * di;
}

// Layer-2 agg as CSR segmented reduction + fused output.
__global__ __launch_bounds__(256) void k_agg1f(const uint2* __restrict__ uptr,
                                               const unsigned* __restrict__ eb2,
                                               const float* __restrict__ g2,
                                               const float* __restrict__ dinv,
                                               const float* __restrict__ b2,
                                               float* __restrict__ out, int n) {
    int tid = threadIdx.x;
    int grp = tid >> 4, j = tid & 15;
    int v = blockIdx.x * 16 + grp;
    if (v >= n) return;
    uint2 pr = uptr[v];
    float a = 0.f;
    for (unsigned i = pr.x + j; i < pr.y; i += 16) a += g2[eb2[i]];
    a += __shfl_down(a, 8, 16);
    a += __shfl_down(a, 4, 16);
    a += __shfl_down(a, 2, 16);
    a += __shfl_down(a, 1, 16);
    if (j == 0) out[v] = dinv[v] * (g2[v] + a) + b2[0];
}

extern "C" void kernel_launch(void* const* d_in, const int* in_sizes, int n_in,
                              void* d_out, int out_size, void* d_ws, size_t ws_size,
                              hipStream_t stream) {
    const float* x   = (const float*)d_in[0];
    const float* ea  = (const float*)d_in[1];
    const int*   row = (const int*)d_in[2];
    const int*   col = (const int*)d_in[3];
    const float* W1  = (const float*)d_in[4];
    const float* b1  = (const float*)d_in[5];
    const float* W2  = (const float*)d_in[6];
    const float* b2  = (const float*)d_in[7];
    float* out = (float*)d_out;

    int n  = in_sizes[0] / D_FEAT;   // 100000
    int ne = in_sizes[2];            // 6400000
    int nb = (n + 255) >> 8;         // 391 buckets of 256 nodes

    float* ws   = (float*)d_ws;
    float* xe   = ws;                      // n
    float* dinv = ws + (size_t)n;          // n
    float* g    = ws + (size_t)2 * n;      // 16n
    float* g2   = ws + (size_t)18 * n;     // n
    unsigned short* gbuf = (unsigned short*)(ws + (size_t)19 * n);  // 16n ushort = 8n floats
    uint2*    uptr  = (uint2*)(ws + (size_t)27 * n);       // n uint2 = 2n
    unsigned* gcur  = (unsigned*)(ws + (size_t)29 * n);    // nb*16
    unsigned* ebufP  = gcur + (size_t)nb * 16;             // nb*CAP
    unsigned* ebuf2P = ebufP + (size_t)nb * CAP;           // nb*CAP

    dim3 blk(256);
    int g_node = (n + 255) / 256;
    int g_tile = (ne + TILE - 1) / TILE;
    int g_gemm = (n + 63) / 64;
    int g_n16  = (n + 15) / 16;

    k_init<<<g_node, blk, 0, stream>>>(xe, gcur, n, nb);
    k_sortplace<<<g_tile, 512, 0, stream>>>(row, col, ea, xe, gcur, ebufP, ne, nb);
    k_csr2<<<nb, 1024, 0, stream>>>(ebufP, gcur, uptr, dinv, ebuf2P, n, nb);
    k_gemm1<<<g_gemm, blk, 0, stream>>>(x, xe, dinv, W1, g, gbuf, n);
    k_agg16g<<<g_n16, blk, 0, stream>>>(uptr, ebuf2P, (const unsigned*)gbuf, g, dinv, b1, W2, g2, n);
    k_agg1f<<<g_n16, blk, 0, stream>>>(uptr, ebuf2P, g2, dinv, b2, out, n);
}